// Round 1
// baseline (1250.196 us; speedup 1.0000x reference)
//
#include <hip/hip_runtime.h>

#define NUME 20000
#define NUMR 8
#define DIM 256
#define DEEPTH 2
#define BATCH 2048
#define NEDGE 500000
#define RRR 16
#define NSEG (NUME*RRR)

typedef unsigned short u16;
typedef unsigned int u32;
typedef __attribute__((ext_vector_type(8))) short short8;
typedef __attribute__((ext_vector_type(4))) float f32x4;

__device__ __forceinline__ float bf2f(u16 u){ return __uint_as_float(((u32)u)<<16); }
__device__ __forceinline__ u16 f2bf(float f){
  u32 u = __float_as_uint(f);
  u += 0x7fffu + ((u>>16)&1u);   // round-to-nearest-even
  return (u16)(u>>16);
}

// ---------------- degree / CSR build ----------------

__global__ void count_kernel(const int* __restrict__ es, const int* __restrict__ ed,
                             const int* __restrict__ er, int* __restrict__ co, int* __restrict__ ci)
{
  const int e = blockIdx.x*256 + threadIdx.x;
  if (e >= NEDGE) return;
  const int r = er[e];
  atomicAdd(&co[r*NUME + es[e]], 1);
  atomicAdd(&ci[r*NUME + ed[e]], 1);
}

__global__ void degs_kernel(const int* __restrict__ co, const int* __restrict__ ci,
                            float* __restrict__ rdo, float* __restrict__ rdi, int* __restrict__ segcnt)
{
  const int i = blockIdx.x*256 + threadIdx.x;
  if (i >= NSEG) return;
  const int r = i / NUME, n = i - r*NUME;
  int dout, din;
  if (r < NUMR){ dout = co[i]; din = ci[i]; }
  else { dout = ci[(r-NUMR)*NUME + n]; din = co[(r-NUMR)*NUME + n]; }
  rdo[i] = rsqrtf((float)(dout > 0 ? dout : 1));
  rdi[i] = rsqrtf((float)(din  > 0 ? din  : 1));
  segcnt[n*RRR + r] = din;   // node-major segment counts (raw, unclamped)
}

__global__ __launch_bounds__(256) void scan_block_kernel(const int* __restrict__ in,
                                                         int* __restrict__ out, int* __restrict__ bsum)
{
  __shared__ int sh[256];
  const int t = threadIdx.x;
  const int base = blockIdx.x*2048 + t*8;
  int pre[8], sum = 0;
#pragma unroll
  for (int j=0;j<8;j++){
    int v = (base+j < NSEG) ? in[base+j] : 0;
    pre[j] = sum; sum += v;
  }
  sh[t] = sum; __syncthreads();
  for (int off=1; off<256; off<<=1){
    int x = (t>=off) ? sh[t-off] : 0;
    __syncthreads();
    sh[t] += x;
    __syncthreads();
  }
  const int excl = sh[t] - sum;
#pragma unroll
  for (int j=0;j<8;j++)
    if (base+j < NSEG) out[base+j] = excl + pre[j];
  if (t==255) bsum[blockIdx.x] = sh[255];
}

__global__ void scan_mid_kernel(const int* __restrict__ bsum, int* __restrict__ boff, int nb)
{
  __shared__ int sh[256];
  const int t = threadIdx.x;
  const int v = (t<nb) ? bsum[t] : 0;
  sh[t] = v; __syncthreads();
  for (int off=1; off<256; off<<=1){
    int x = (t>=off) ? sh[t-off] : 0;
    __syncthreads();
    sh[t] += x;
    __syncthreads();
  }
  boff[t] = sh[t] - v;
}

__global__ void scan_add_kernel(int* __restrict__ out, const int* __restrict__ boff,
                                int* __restrict__ cursor)
{
  const int i = blockIdx.x*256 + threadIdx.x;
  if (i < NSEG){
    const int v = out[i] + boff[i>>11];
    out[i] = v;
    cursor[i] = v;
  } else if (i == NSEG){
    out[i] = 2*NEDGE;
  }
}

__global__ void fill_kernel(const int* __restrict__ es, const int* __restrict__ ed,
                            const int* __restrict__ er, int* __restrict__ cursor, int* __restrict__ csr)
{
  const int e = blockIdx.x*256 + threadIdx.x;
  if (e >= NEDGE) return;
  const int r = er[e], s = es[e], d = ed[e];
  int p = atomicAdd(&cursor[d*RRR + r], 1);          // forward msg s -> d, rel r
  csr[p] = s;
  p = atomicAdd(&cursor[s*RRR + NUMR + r], 1);       // reverse msg d -> s, rel r+8
  csr[p] = d;
}

// ---------------- weight prep ----------------

// in: [z][K][N] f32  ->  out: [z][N][K] bf16
__global__ __launch_bounds__(256) void transpose_kernel(const float* __restrict__ in,
                                                        u16* __restrict__ out, int K, int N)
{
  __shared__ float tile[32][33];
  const long zo = (long)blockIdx.z * K * N;
  const int nb = blockIdx.x*32, kb = blockIdx.y*32;
  const int tx = threadIdx.x & 31, ty = threadIdx.x >> 5;
#pragma unroll
  for (int i=ty; i<32; i+=8){
    const int k = kb+i, n = nb+tx;
    tile[i][tx] = (k<K && n<N) ? in[zo + (long)k*N + n] : 0.f;
  }
  __syncthreads();
#pragma unroll
  for (int i=ty; i<32; i+=8){
    const int n = nb+i, k = kb+tx;
    if (n<N && k<K) out[zo + (long)n*K + k] = f2bf(tile[tx][i]);
  }
}

__global__ void meanb_kernel(const float* __restrict__ bconv, float* __restrict__ mb)
{
  const int i = threadIdx.x + blockIdx.x*256;
  if (i >= DEEPTH*DIM) return;
  const int l = i / DIM, d = i - l*DIM;
  float s = 0.f;
#pragma unroll
  for (int r=0;r<RRR;r++) s += bconv[(l*RRR + r)*DIM + d];
  mb[i] = s * (1.f/16.f);
}

__global__ void cvt_bf16_kernel(const float* __restrict__ in, u16* __restrict__ out, int n4)
{
  const int i = blockIdx.x*256 + threadIdx.x;
  if (i >= n4) return;
  const float4 v = *(const float4*)&in[(long)i*4];
  ushort4 o; o.x=f2bf(v.x); o.y=f2bf(v.y); o.z=f2bf(v.z); o.w=f2bf(v.w);
  *(ushort4*)&out[(long)i*4] = o;
}

// ---------------- GEMM (m97 structure: 128x128 tile, BK=32, 4 waves) ----------------
// A: [M][K] bf16 row-major; B: [N][K] bf16 (i.e. B^T); C: [M][ldc] (f32 or bf16)

template<bool OUT_BF16, bool HAS_BIAS>
__global__ __launch_bounds__(256) void gemm_kernel(
    const u16* __restrict__ A, long sAb,
    const u16* __restrict__ B, long sBb,
    void* __restrict__ Cv, long sCb,
    const float* __restrict__ bias,
    int M, int N, int K, int ldc)
{
  __shared__ alignas(16) u16 shA[128*32];
  __shared__ alignas(16) u16 shB[128*32];
  const int m0 = blockIdx.x*128, n0 = blockIdx.y*128;
  A += sAb*blockIdx.z; B += sBb*blockIdx.z;
  const int tid = threadIdx.x;
  const int lane = tid & 63, wave = tid >> 6;
  const int wm = wave >> 1, wn = wave & 1;
  const int lr = lane >> 2, lc = lane & 3;
  f32x4 acc[4][4];
#pragma unroll
  for (int i=0;i<4;i++)
#pragma unroll
    for (int j=0;j<4;j++) acc[i][j] = (f32x4){0.f,0.f,0.f,0.f};

  for (int k0=0; k0<K; k0+=32){
#pragma unroll
    for (int t=0;t<2;t++){
      const int rg = (wave*2+t)*16;          // 16-row group, wave-uniform
      int ra = m0 + rg + lr; ra = ra < M ? ra : M-1;
      const u16* pa = A + (long)ra*K + (k0 + lc*8);
      __builtin_amdgcn_global_load_lds((const __attribute__((address_space(1))) void*)pa,
          (__attribute__((address_space(3))) void*)&shA[rg*32], 16, 0, 0);
      int rb = n0 + rg + lr; rb = rb < N ? rb : N-1;
      const u16* pb = B + (long)rb*K + (k0 + lc*8);
      __builtin_amdgcn_global_load_lds((const __attribute__((address_space(1))) void*)pb,
          (__attribute__((address_space(3))) void*)&shB[rg*32], 16, 0, 0);
    }
    __syncthreads();
    short8 fa[4], fb[4];
#pragma unroll
    for (int f=0; f<4; f++){
      fa[f] = *(const short8*)&shA[(wm*64 + f*16 + (lane&15))*32 + (lane>>4)*8];
      fb[f] = *(const short8*)&shB[(wn*64 + f*16 + (lane&15))*32 + (lane>>4)*8];
    }
#pragma unroll
    for (int i=0;i<4;i++)
#pragma unroll
      for (int j=0;j<4;j++)
        acc[i][j] = __builtin_amdgcn_mfma_f32_16x16x32_bf16(fa[i], fb[j], acc[i][j], 0, 0, 0);
    __syncthreads();
  }

  // C/D mapping (m89-verified): col = lane&15, row = (lane>>4)*4 + q
  const int r0 = m0 + wm*64 + (lane>>4)*4;
  const int c0 = n0 + wn*64 + (lane&15);
#pragma unroll
  for (int i=0;i<4;i++){
#pragma unroll
    for (int j=0;j<4;j++){
      const int col = c0 + j*16;
      if (col < N){
        float bv = HAS_BIAS ? bias[col] : 0.f;
#pragma unroll
        for (int q=0;q<4;q++){
          const int row = r0 + i*16 + q;
          if (row < M){
            const float v = acc[i][j][q] + bv;
            if (OUT_BF16) ((u16*)Cv)[sCb*blockIdx.z + (long)row*ldc + col] = f2bf(v);
            else          ((float*)Cv)[sCb*blockIdx.z + (long)row*ldc + col] = v;
          }
        }
      }
    }
  }
}

// ---------------- aggregation (1 wave per node, CSR, no atomics) ----------------

__global__ __launch_bounds__(256) void aggregate_kernel(
    const u16* __restrict__ gh,      // [16][NUME][DIM] bf16
    const int* __restrict__ csr,     // [2*NEDGE]
    const int* __restrict__ segoff,  // [NSEG+1], node-major n*16+r
    const float* __restrict__ rdo,   // [16][NUME]
    const float* __restrict__ rdi,   // [16][NUME]
    const float* __restrict__ mb,    // [DIM]
    float* __restrict__ hout)        // [NUME][DIM]
{
  const int lane = threadIdx.x & 63;
  const int n = blockIdx.x*4 + (threadIdx.x>>6);
  if (n >= NUME) return;
  float a0=0.f,a1=0.f,a2=0.f,a3=0.f;
  const int base = n*RRR;
#pragma unroll 1
  for (int r=0;r<RRR;r++){
    const int e0 = segoff[base+r], e1 = segoff[base+r+1];
    if (e0 == e1) continue;
    float p0=0.f,p1=0.f,p2=0.f,p3=0.f;
    const long slab = (long)r*NUME;
    for (int e=e0;e<e1;e++){
      const int s = csr[e];
      const float w = rdo[r*NUME + s];
      const ushort4 v = *(const ushort4*)&gh[(slab + s)*DIM + lane*4];
      p0 += w*bf2f(v.x); p1 += w*bf2f(v.y); p2 += w*bf2f(v.z); p3 += w*bf2f(v.w);
    }
    const float wi = rdi[r*NUME + n];
    a0 += wi*p0; a1 += wi*p1; a2 += wi*p2; a3 += wi*p3;
  }
  const float inv = 1.f/16.f;
  float4 o;
  o.x = a0*inv + mb[lane*4+0];
  o.y = a1*inv + mb[lane*4+1];
  o.z = a2*inv + mb[lane*4+2];
  o.w = a3*inv + mb[lane*4+3];
  *(float4*)&hout[(long)n*DIM + lane*4] = o;
}

// ---------------- build concatenated A for final GEMMs ----------------

__global__ void build_cat_kernel(const float* __restrict__ h, const int* __restrict__ idx,
                                 const int* __restrict__ rel, const float* __restrict__ rel_emb,
                                 u16* __restrict__ Aout)
{
  const int i = blockIdx.x*256 + threadIdx.x;
  if (i >= BATCH*512) return;
  const int row = i >> 9, col = i & 511;
  float v;
  if (col < DIM) v = h[(long)idx[row]*DIM + col];
  else           v = rel_emb[(long)rel[row]*DIM + (col-DIM)];
  Aout[i] = f2bf(v);
}

// ---------------- launch ----------------

extern "C" void kernel_launch(void* const* d_in, const int* in_sizes, int n_in,
                              void* d_out, int out_size, void* d_ws, size_t ws_size,
                              hipStream_t stream)
{
  (void)in_sizes; (void)n_in; (void)out_size; (void)ws_size;
  const float* entity = (const float*)d_in[0];
  const float* Wconv  = (const float*)d_in[1];
  const float* bconv  = (const float*)d_in[2];
  const float* sre    = (const float*)d_in[3];
  const float* ore    = (const float*)d_in[4];
  const float* Wsub   = (const float*)d_in[5];
  const float* bsub   = (const float*)d_in[6];
  const float* Wobj   = (const float*)d_in[7];
  const float* bobj   = (const float*)d_in[8];
  const int*   sub    = (const int*)d_in[9];
  const int*   obj    = (const int*)d_in[10];
  const int*   rel    = (const int*)d_in[11];
  const int*   esrc   = (const int*)d_in[12];
  const int*   edst   = (const int*)d_in[13];
  const int*   erel   = (const int*)d_in[14];
  float* out = (float*)d_out;

  char* w = (char*)d_ws;
  auto alloc = [&](size_t b)->void*{ void* p = (void*)w; w += (b + 255) & ~(size_t)255; return p; };
  int*   cnts   = (int*)alloc((size_t)2*NUMR*NUME*4);
  int*   cnt_out = cnts;
  int*   cnt_in  = cnts + NUMR*NUME;
  float* rdo    = (float*)alloc((size_t)NSEG*4);
  float* rdi    = (float*)alloc((size_t)NSEG*4);
  int*   segcnt = (int*)alloc((size_t)NSEG*4);
  int*   segoff = (int*)alloc((size_t)(NSEG+1)*4);
  int*   cursor = (int*)alloc((size_t)NSEG*4);
  int*   bsum   = (int*)alloc(1024*4);
  int*   boff   = (int*)alloc(1024*4);
  int*   csr    = (int*)alloc((size_t)2*NEDGE*4);
  float* h1     = (float*)alloc((size_t)NUME*DIM*4);
  float* h2     = (float*)alloc((size_t)NUME*DIM*4);
  u16*   hbf    = (u16*)alloc((size_t)NUME*DIM*2);
  u16*   gh     = (u16*)alloc((size_t)RRR*NUME*DIM*2);
  u16*   Wct    = (u16*)alloc((size_t)DEEPTH*RRR*DIM*DIM*2);
  u16*   Wsubt  = (u16*)alloc((size_t)512*NUME*2);
  u16*   Wobjt  = (u16*)alloc((size_t)512*NUME*2);
  float* mb     = (float*)alloc((size_t)DEEPTH*DIM*4);
  u16*   Asub   = (u16*)alloc((size_t)BATCH*512*2);
  u16*   Aobj   = (u16*)alloc((size_t)BATCH*512*2);

  // CSR + degrees (edges are layer-invariant: build once per launch)
  hipMemsetAsync(cnts, 0, (size_t)2*NUMR*NUME*4, stream);
  count_kernel<<<(NEDGE+255)/256, 256, 0, stream>>>(esrc, edst, erel, cnt_out, cnt_in);
  degs_kernel<<<(NSEG+255)/256, 256, 0, stream>>>(cnt_out, cnt_in, rdo, rdi, segcnt);
  const int nblk = (NSEG + 2047)/2048;
  scan_block_kernel<<<nblk, 256, 0, stream>>>(segcnt, segoff, bsum);
  scan_mid_kernel<<<1, 256, 0, stream>>>(bsum, boff, nblk);
  scan_add_kernel<<<(NSEG+1+255)/256, 256, 0, stream>>>(segoff, boff, cursor);
  fill_kernel<<<(NEDGE+255)/256, 256, 0, stream>>>(esrc, edst, erel, cursor, csr);

  // weights -> [N][K] bf16
  transpose_kernel<<<dim3(DIM/32, DIM/32, DEEPTH*RRR), 256, 0, stream>>>(Wconv, Wct, DIM, DIM);
  transpose_kernel<<<dim3(NUME/32, 512/32, 1), 256, 0, stream>>>(Wsub, Wsubt, 512, NUME);
  transpose_kernel<<<dim3(NUME/32, 512/32, 1), 256, 0, stream>>>(Wobj, Wobjt, 512, NUME);
  meanb_kernel<<<2, 256, 0, stream>>>(bconv, mb);

  const int n4 = NUME*DIM/4;
  const int mt = (NUME + 127)/128;   // 157

  // layer 0: gh_r = h @ W_r  (transform-first), then CSR aggregate
  cvt_bf16_kernel<<<(n4+255)/256, 256, 0, stream>>>(entity, hbf, n4);
  gemm_kernel<true,false><<<dim3(mt, DIM/128, RRR), 256, 0, stream>>>(
      hbf, 0, Wct, (long)DIM*DIM, gh, (long)NUME*DIM, nullptr, NUME, DIM, DIM, DIM);
  aggregate_kernel<<<NUME/4, 256, 0, stream>>>(gh, csr, segoff, rdo, rdi, mb, h1);

  // layer 1
  cvt_bf16_kernel<<<(n4+255)/256, 256, 0, stream>>>(h1, hbf, n4);
  gemm_kernel<true,false><<<dim3(mt, DIM/128, RRR), 256, 0, stream>>>(
      hbf, 0, Wct + (size_t)RRR*DIM*DIM, (long)DIM*DIM, gh, (long)NUME*DIM, nullptr, NUME, DIM, DIM, DIM);
  aggregate_kernel<<<NUME/4, 256, 0, stream>>>(gh, csr, segoff, rdo, rdi, mb + DIM, h2);

  // scoring: sub_predict = [h[obj], ore] @ W_sub + b_sub ; obj_predict = [h[sub], sre] @ W_obj + b_obj
  build_cat_kernel<<<BATCH*512/256, 256, 0, stream>>>(h2, obj, rel, ore, Asub);
  build_cat_kernel<<<BATCH*512/256, 256, 0, stream>>>(h2, sub, rel, sre, Aobj);

  gemm_kernel<false,true><<<dim3(BATCH/128, (NUME+127)/128, 1), 256, 0, stream>>>(
      Asub, 0, Wsubt, 0, out, 0, bsub, BATCH, NUME, 512, NUME);
  gemm_kernel<false,true><<<dim3(BATCH/128, (NUME+127)/128, 1), 256, 0, stream>>>(
      Aobj, 0, Wobjt, 0, out + (size_t)BATCH*NUME, 0, bobj, BATCH, NUME, 512, NUME);
}